// Round 9
// baseline (371.902 us; speedup 1.0000x reference)
//
#include <hip/hip_runtime.h>
#include <hip/hip_bf16.h>
#include <stdint.h>

#define D_MODEL 1024
#define NHEAD   16
#define DH      64

typedef __attribute__((ext_vector_type(8))) short bf16x8;
typedef __attribute__((ext_vector_type(4))) float f32x4;

__device__ __forceinline__ ushort f2bf(float f) {
    __hip_bfloat16 h = __float2bfloat16(f);
    return *reinterpret_cast<ushort*>(&h);
}

__device__ __forceinline__ void gload_lds16(const void* g, void* l) {
    __builtin_amdgcn_global_load_lds(
        (const __attribute__((address_space(1))) void*)g,
        (__attribute__((address_space(3))) void*)l, 16, 0, 0);
}

// Load 8 contiguous fp32, convert to bf16x8 in-register.
__device__ __forceinline__ bf16x8 load8f(const float* p) {
    const float4 a = *(const float4*)p;
    const float4 b = *(const float4*)(p + 4);
    bf16x8 r;
    r[0] = (short)f2bf(a.x); r[1] = (short)f2bf(a.y);
    r[2] = (short)f2bf(a.z); r[3] = (short)f2bf(a.w);
    r[4] = (short)f2bf(b.x); r[5] = (short)f2bf(b.y);
    r[6] = (short)f2bf(b.z); r[7] = (short)f2bf(b.w);
    return r;
}

// fp32 -> bf16 weight conversion: 4 matrices of 1M elements each.
__global__ __launch_bounds__(256) void cvt_w_kernel(
    const float* __restrict__ w0, const float* __restrict__ w1,
    const float* __restrict__ w2, const float* __restrict__ w3,
    ushort* __restrict__ out)
{
    const int g = blockIdx.x * 256 + threadIdx.x;   // group of 8 elems
    const int m = g >> 17;                          // 131072 groups / matrix
    const int off = (g & 131071) * 8;
    const float* src = (m == 0) ? w0 : (m == 1) ? w1 : (m == 2) ? w2 : w3;
    *(bf16x8*)(out + (size_t)m * 1048576 + off) = load8f(src + off);
}

__device__ __forceinline__ void storeC(float*  C, size_t i, float v) { C[i] = v; }
__device__ __forceinline__ void storeC(ushort* C, size_t i, float v) { C[i] = (short)f2bf(v); }

// C = X(MxK) @ Wb^T (Wb NxK bf16) + bias. A_F32: X fp32 (explicit staging);
// else X bf16 (global_load_lds). B always via global_load_lds.
template<bool A_F32, typename TX, typename TOUT>
__device__ __forceinline__ void gemm_core(
    const TX* __restrict__ X,
    const ushort* __restrict__ Wb,
    const float* __restrict__ Bias,
    TOUT* __restrict__ C,
    int M, int N, int K,
    short* As, short* Bs)
{
    const int tid  = threadIdx.x;
    const int w    = tid >> 6;
    const int lane = tid & 63;
    const int quad = lane >> 4;
    const int l15  = lane & 15;
    const int wr   = w >> 1, wc = w & 1;
    const int m0 = blockIdx.y * 128;
    const int n0 = blockIdx.x * 128;

    f32x4 acc[4][4] = {};

    for (int k0 = 0; k0 < K; k0 += 32) {
        __syncthreads();
        #pragma unroll
        for (int c = 0; c < 2; ++c) {
            int chunk = w * 2 + c;
            int row   = chunk * 16 + (lane >> 2);
            gload_lds16(Wb + (size_t)(n0 + row) * K + k0 + (lane & 3) * 8,
                        &Bs[chunk * 512]);
        }
        if (A_F32) {
            #pragma unroll
            for (int c = 0; c < 2; ++c) {
                int idx = c * 256 + tid;
                int row = idx >> 2;
                int col = (idx & 3) * 8;
                *(bf16x8*)&As[row * 32 + col] =
                    load8f((const float*)X + (size_t)(m0 + row) * K + k0 + col);
            }
        } else {
            #pragma unroll
            for (int c = 0; c < 2; ++c) {
                int chunk = w * 2 + c;
                int row   = chunk * 16 + (lane >> 2);
                gload_lds16((const ushort*)X + (size_t)(m0 + row) * K + k0 + (lane & 3) * 8,
                            &As[chunk * 512]);
            }
        }
        __syncthreads();

        bf16x8 af[4], bfr[4];
        #pragma unroll
        for (int i = 0; i < 4; ++i)
            af[i] = *(const bf16x8*)&As[(wr * 64 + i * 16 + l15) * 32 + quad * 8];
        #pragma unroll
        for (int j = 0; j < 4; ++j)
            bfr[j] = *(const bf16x8*)&Bs[(wc * 64 + j * 16 + l15) * 32 + quad * 8];
        #pragma unroll
        for (int i = 0; i < 4; ++i)
            #pragma unroll
            for (int j = 0; j < 4; ++j)
                acc[i][j] = __builtin_amdgcn_mfma_f32_16x16x32_bf16(af[i], bfr[j], acc[i][j], 0, 0, 0);
    }

    float bias[4];
    #pragma unroll
    for (int j = 0; j < 4; ++j)
        bias[j] = Bias[n0 + wc * 64 + j * 16 + l15];

    #pragma unroll
    for (int i = 0; i < 4; ++i) {
        int row = m0 + wr * 64 + i * 16 + quad * 4;
        #pragma unroll
        for (int j = 0; j < 4; ++j) {
            int col = n0 + wc * 64 + j * 16 + l15;
            #pragma unroll
            for (int r = 0; r < 4; ++r)
                storeC(C, (size_t)(row + r) * N + col, acc[i][j][r] + bias[j]);
        }
    }
}

__global__ __launch_bounds__(256) void qkv_proj_kernel(
    const float* __restrict__ Qin, const float* __restrict__ Kin,
    const float* __restrict__ Vin,
    const ushort* __restrict__ Wb,
    const float* __restrict__ Bq, const float* __restrict__ Bk,
    const float* __restrict__ Bv,
    ushort* qo, ushort* ko, ushort* vo, int L)
{
    __shared__ short As[4096];
    __shared__ short Bs[4096];
    const int z = blockIdx.z;
    const float *X, *B; ushort* C;
    if (z == 0)      { X = Qin; B = Bq; C = qo; }
    else if (z == 1) { X = Kin; B = Bk; C = ko; }
    else             { X = Vin; B = Bv; C = vo; }
    gemm_core<true, float, ushort>(X, Wb + (size_t)z * 1048576, B, C,
                                   L, D_MODEL, D_MODEL, As, Bs);
}

__global__ __launch_bounds__(256) void out_proj_kernel(
    const ushort* __restrict__ Xa, const ushort* __restrict__ Wb,
    const float* __restrict__ Bo, float* out, int L)
{
    __shared__ short As[4096];
    __shared__ short Bs[4096];
    gemm_core<false, ushort, float>(Xa, Wb + (size_t)3 * 1048576, Bo, out,
                                    L, D_MODEL, D_MODEL, As, Bs);
}

// Flash attention v3: transposed scores + 2 q-tiles per wave (K/V fragment
// reuse). Block = 4 waves x 32 q = 128 q rows, 256 threads. Grid (L/128, H).
__global__ __launch_bounds__(256) void attn_kernel(
    const ushort* __restrict__ Qw,
    const ushort* __restrict__ Kw,
    const ushort* __restrict__ Vw,
    ushort* __restrict__ Ow, int L)
{
    __shared__ short Ks[64 * 64];          // [key][dh]  swizzled
    __shared__ short Vs[64 * 64];          // [dh][key]  swizzled
    __shared__ short Ps[4][2][16 * 64];    // [wave][qtile][q][key swizzled]

    const int tid  = threadIdx.x;
    const int w    = tid >> 6;             // 0..3
    const int lane = tid & 63;
    const int quad = lane >> 4;
    const int l15  = lane & 15;
    const int h    = blockIdx.y;
    const int q0   = blockIdx.x * 128;

    // Q fragments for both q-tiles (B-operand; [l15][quad*8+j] mapping)
    bf16x8 qf[2][2];
    #pragma unroll
    for (int u = 0; u < 2; ++u) {
        const ushort* qp = Qw + (size_t)(q0 + w * 32 + u * 16 + l15) * D_MODEL + h * DH + quad * 8;
        qf[u][0] = *(const bf16x8*)(qp);
        qf[u][1] = *(const bf16x8*)(qp + 32);
    }

    const int krswz0 = ((quad    ) ^ (l15 & 7)) * 8;
    const int krswz1 = ((quad + 4) ^ (l15 & 7)) * 8;

    f32x4 o[2][4] = {};
    float m_run[2] = {-3e38f, -3e38f};
    float l_run[2] = {0.f, 0.f};
    const float csc = 0.125f * 1.44269504088896f;   // log2(e)/sqrt(Dh)

    for (int key0 = 0; key0 < L; key0 += 64) {
        __syncthreads();   // WAR on Ks/Vs
        // K stage: 512 slots of 16B, 2 per thread, swizzled group8
        #pragma unroll
        for (int c = 0; c < 2; ++c) {
            int s   = c * 256 + tid;
            int key = s >> 3;
            int gl  = s & 7;
            *(bf16x8*)&Ks[key * 64 + ((gl ^ (key & 7)) * 8)] =
                *(const bf16x8*)(Kw + (size_t)(key0 + key) * D_MODEL + h * DH + gl * 8);
        }
        // V stage (transpose): lane = key; wave+c pick dh-octet
        #pragma unroll
        for (int c = 0; c < 2; ++c) {
            int vdh = c * 32 + w * 8;
            bf16x8 vv = *(const bf16x8*)(Vw + (size_t)(key0 + lane) * D_MODEL + h * DH + vdh);
            #pragma unroll
            for (int i = 0; i < 8; ++i)
                Vs[(vdh + i) * 64 + (((lane >> 3) ^ i) * 8) + (lane & 7)] = vv[i];
        }
        __syncthreads();

        // St = K·Q^T for both q-tiles; K-fragments shared across tiles
        f32x4 st[2][4];
        #pragma unroll
        for (int kt = 0; kt < 4; ++kt) {
            const int kr = (kt * 16 + l15) * 64;
            bf16x8 kf0 = *(const bf16x8*)&Ks[kr + krswz0];
            bf16x8 kf1 = *(const bf16x8*)&Ks[kr + krswz1];
            #pragma unroll
            for (int u = 0; u < 2; ++u) {
                f32x4 z = {};
                z = __builtin_amdgcn_mfma_f32_16x16x32_bf16(kf0, qf[u][0], z, 0, 0, 0);
                z = __builtin_amdgcn_mfma_f32_16x16x32_bf16(kf1, qf[u][1], z, 0, 0, 0);
                st[u][kt] = z;
            }
        }

        // online softmax per q-tile (lane l15 = query within tile)
        #pragma unroll
        for (int u = 0; u < 2; ++u) {
            float mx = st[u][0][0];
            #pragma unroll
            for (int kt = 0; kt < 4; ++kt)
                #pragma unroll
                for (int r = 0; r < 4; ++r)
                    mx = fmaxf(mx, st[u][kt][r]);
            mx = fmaxf(mx, __shfl_xor(mx, 16));
            mx = fmaxf(mx, __shfl_xor(mx, 32));
            const float mnew  = fmaxf(m_run[u], mx);
            const float alpha = __builtin_amdgcn_exp2f((m_run[u] - mnew) * csc);
            m_run[u] = mnew;

            float rs = 0.f;
            #pragma unroll
            for (int kt = 0; kt < 4; ++kt) {
                float p0 = __builtin_amdgcn_exp2f((st[u][kt][0] - mnew) * csc);
                float p1 = __builtin_amdgcn_exp2f((st[u][kt][1] - mnew) * csc);
                float p2 = __builtin_amdgcn_exp2f((st[u][kt][2] - mnew) * csc);
                float p3 = __builtin_amdgcn_exp2f((st[u][kt][3] - mnew) * csc);
                rs += (p0 + p1) + (p2 + p3);
                uint2 pk;
                pk.x = (uint32_t)f2bf(p0) | ((uint32_t)f2bf(p1) << 16);
                pk.y = (uint32_t)f2bf(p2) | ((uint32_t)f2bf(p3) << 16);
                const int G = kt * 2 + (quad >> 1);
                *(uint2*)&Ps[w][u][l15 * 64 + ((G ^ (l15 & 7)) * 8) + (quad & 1) * 4] = pk;
            }
            rs += __shfl_xor(rs, 16);
            rs += __shfl_xor(rs, 32);
            l_run[u] = l_run[u] * alpha + rs;

            // alpha -> O-row positions
            float a[4];
            #pragma unroll
            for (int r = 0; r < 4; ++r)
                a[r] = __shfl(alpha, (lane & 48) | (quad * 4 + r));
            #pragma unroll
            for (int dt = 0; dt < 4; ++dt)
                #pragma unroll
                for (int r = 0; r < 4; ++r)
                    o[u][dt][r] *= a[r];
        }
        // no barrier: Ps[w] wave-private; per-wave DS ops in order

        // O += P·V; V-fragments shared across q-tiles
        #pragma unroll
        for (int f = 0; f < 2; ++f) {
            bf16x8 pf[2];
            #pragma unroll
            for (int u = 0; u < 2; ++u)
                pf[u] = *(const bf16x8*)&Ps[w][u][l15 * 64 + (((f * 4 + quad) ^ (l15 & 7)) * 8)];
            #pragma unroll
            for (int dt = 0; dt < 4; ++dt) {
                bf16x8 vf = *(const bf16x8*)&Vs[(dt * 16 + l15) * 64 + (((f * 4 + quad) ^ (l15 & 7)) * 8)];
                #pragma unroll
                for (int u = 0; u < 2; ++u)
                    o[u][dt] = __builtin_amdgcn_mfma_f32_16x16x32_bf16(pf[u], vf, o[u][dt], 0, 0, 0);
            }
        }
    }

    #pragma unroll
    for (int u = 0; u < 2; ++u) {
        const float inv = 1.f / l_run[u];
        #pragma unroll
        for (int r = 0; r < 4; ++r) {
            const float linv = __shfl(inv, (lane & 48) | (quad * 4 + r));
            const int row = q0 + w * 32 + u * 16 + quad * 4 + r;
            #pragma unroll
            for (int dt = 0; dt < 4; ++dt) {
                int col = h * DH + dt * 16 + l15;
                Ow[(size_t)row * D_MODEL + col] = (short)f2bf(o[u][dt][r] * linv);
            }
        }
    }
}

extern "C" void kernel_launch(void* const* d_in, const int* in_sizes, int n_in,
                              void* d_out, int out_size, void* d_ws, size_t ws_size,
                              hipStream_t stream) {
    const float* Q   = (const float*)d_in[0];
    const float* K   = (const float*)d_in[1];
    const float* V   = (const float*)d_in[2];
    const float* w_q = (const float*)d_in[3];
    const float* b_q = (const float*)d_in[4];
    const float* w_k = (const float*)d_in[5];
    const float* b_k = (const float*)d_in[6];
    const float* w_v = (const float*)d_in[7];
    const float* b_v = (const float*)d_in[8];
    const float* w_o = (const float*)d_in[9];
    const float* b_o = (const float*)d_in[10];
    float* out = (float*)d_out;

    const int L = in_sizes[0] / D_MODEL;   // 4096
    const size_t mat = (size_t)L * D_MODEL;

    // d_ws [0,8): Wb | [8,16): a_ws | [16,24): v_ws
    // d_out[0,8): q_ws | [8,16): k_ws  (dead before out_proj fp32 write)
    ushort* Wb   = (ushort*)d_ws;
    ushort* a_ws = (ushort*)d_ws + 4 * 1048576;
    ushort* v_ws = a_ws + mat;
    ushort* q_ws = (ushort*)d_out;
    ushort* k_ws = q_ws + mat;

    cvt_w_kernel<<<dim3(2048), dim3(256), 0, stream>>>(w_q, w_k, w_v, w_o, Wb);

    dim3 gqkv(D_MODEL / 128, L / 128, 3);
    qkv_proj_kernel<<<gqkv, dim3(256), 0, stream>>>(Q, K, V, Wb, b_q, b_k, b_v,
                                                    q_ws, k_ws, v_ws, L);
    dim3 gattn(L / 128, NHEAD);
    attn_kernel<<<gattn, dim3(256), 0, stream>>>(q_ws, k_ws, v_ws, a_ws, L);
    dim3 gout(D_MODEL / 128, L / 128);
    out_proj_kernel<<<gout, dim3(256), 0, stream>>>(a_ws, Wb, b_o, out, L);
}